// Round 2
// baseline (311.852 us; speedup 1.0000x reference)
//
#include <hip/hip_runtime.h>
#include <hip/hip_bf16.h>
#include <math.h>

#define B_  2
#define N_  1024
#define C_  512
#define H_  16
#define D_  32
#define NW  27
#define QC  16
#define KC  32

// ---------------- window partition (deterministic, IEEE-matching) ----------------
__global__ __launch_bounds__(1024) void win_kernel(
    const float* __restrict__ coords,
    int* __restrict__ counts, int* __restrict__ offsets, int* __restrict__ sidx)
{
  const int b = blockIdx.x;
  const int i = threadIdx.x;          // 0..1023
  const int lane = i & 63, wv = i >> 6;
  const float c0 = coords[(b*N_+i)*3+0];
  const float c1 = coords[(b*N_+i)*3+1];
  const float c2 = coords[(b*N_+i)*3+2];
  float mn0=c0,mx0=c0,mn1=c1,mx1=c1,mn2=c2,mx2=c2;
  #pragma unroll
  for (int o=32;o>=1;o>>=1) {
    mn0=fminf(mn0,__shfl_xor(mn0,o)); mx0=fmaxf(mx0,__shfl_xor(mx0,o));
    mn1=fminf(mn1,__shfl_xor(mn1,o)); mx1=fmaxf(mx1,__shfl_xor(mx1,o));
    mn2=fminf(mn2,__shfl_xor(mn2,o)); mx2=fmaxf(mx2,__shfl_xor(mx2,o));
  }
  __shared__ float red[16][6];
  __shared__ float bmin[3], rng[3];
  __shared__ int wavecnt[16][NW];
  __shared__ int waveoff[16][NW];
  __shared__ int wcnt[NW], woff[NW];
  if (lane==0){ red[wv][0]=mn0;red[wv][1]=mn1;red[wv][2]=mn2;red[wv][3]=mx0;red[wv][4]=mx1;red[wv][5]=mx2; }
  __syncthreads();
  if (i==0){
    float a0=red[0][0],a1=red[0][1],a2=red[0][2];
    float d0=red[0][3],d1=red[0][4],d2=red[0][5];
    for (int t=1;t<16;++t){
      a0=fminf(a0,red[t][0]); a1=fminf(a1,red[t][1]); a2=fminf(a2,red[t][2]);
      d0=fmaxf(d0,red[t][3]); d1=fmaxf(d1,red[t][4]); d2=fmaxf(d2,red[t][5]);
    }
    bmin[0]=a0;bmin[1]=a1;bmin[2]=a2;
    float r0=d0-a0, r1=d1-a1, r2=d2-a2;
    rng[0]=(r0<1e-6f)?1.f:r0; rng[1]=(r1<1e-6f)?1.f:r1; rng[2]=(r2<1e-6f)?1.f:r2;
  }
  __syncthreads();
  // exact op order of reference: cnorm=(c-cmin)/crange; bin=(int)(cnorm*3); clip
  int bx=(int)(((c0-bmin[0])/rng[0])*3.0f); bx=min(max(bx,0),2);
  int by=(int)(((c1-bmin[1])/rng[1])*3.0f); by=min(max(by,0),2);
  int bz=(int)(((c2-bmin[2])/rng[2])*3.0f); bz=min(max(bz,0),2);
  const int wid = bx*9+by*3+bz;
  unsigned long long mymask=0ull;
  for (int w=0;w<NW;++w){
    unsigned long long m = __ballot(wid==w);
    if (w==wid) mymask=m;
    if (lane==0) wavecnt[wv][w]=(int)__popcll(m);
  }
  __syncthreads();
  if (i<NW){ int s=0; for(int t=0;t<16;++t) s+=wavecnt[t][i]; wcnt[i]=s; }
  __syncthreads();
  if (i==0){ int r=0; for(int w=0;w<NW;++w){ woff[w]=r; r+=wcnt[w]; } }
  __syncthreads();
  if (i<NW){ int o=woff[i]; for(int t=0;t<16;++t){ waveoff[t][i]=o; o+=wavecnt[t][i]; } }
  __syncthreads();
  const int rank = waveoff[wv][wid] + (int)__popcll(mymask & ((1ull<<lane)-1ull));
  sidx[b*N_ + rank] = i;
  if (i<NW){ counts[b*NW+i]=wcnt[i]; offsets[b*NW+i]=woff[i]; }
}

// ---------------- pack pos_w1 rows + pos_b1 into float4 ----------------
__global__ void pack_kernel(const float* __restrict__ pw1, const float* __restrict__ pb1,
                            float4* __restrict__ w14)
{
  const int u = threadIdx.x;
  if (u < 128) w14[u] = make_float4(pw1[u*3+0], pw1[u*3+1], pw1[u*3+2], pb1[u]);
}

// ---------------- f32 tiled GEMM: Y = X @ W^T + bias ----------------
// X: M x K,  W: Nd x K,  Y: M x Nd.  All dims multiples of 128/16 here.
__global__ __launch_bounds__(256) void gemm_bt(
    const float* __restrict__ X, const float* __restrict__ W,
    const float* __restrict__ bias, float* __restrict__ Y,
    const int M, const int Nd, const int K)
{
  __shared__ float Xs[16][132];
  __shared__ float Ws[16][132];
  const int tid = threadIdx.x;
  const int bm = blockIdx.x*128, bn = blockIdx.y*128;
  const int tcol = (tid & 15)*8, trow = (tid >> 4)*8;
  float acc[8][8];
  #pragma unroll
  for (int i=0;i<8;++i)
    #pragma unroll
    for (int j=0;j<8;++j) acc[i][j]=0.f;

  for (int k0=0;k0<K;k0+=16){
    #pragma unroll
    for (int t=0;t<2;++t){
      const int id4 = tid + t*256;          // 0..511 float4 slots
      const int row = id4 >> 2;
      const int c4  = (id4 & 3)*4;
      const float4 xv = *(const float4*)(X + (size_t)(bm+row)*K + k0 + c4);
      Xs[c4+0][row]=xv.x; Xs[c4+1][row]=xv.y; Xs[c4+2][row]=xv.z; Xs[c4+3][row]=xv.w;
      const float4 wvv = *(const float4*)(W + (size_t)(bn+row)*K + k0 + c4);
      Ws[c4+0][row]=wvv.x; Ws[c4+1][row]=wvv.y; Ws[c4+2][row]=wvv.z; Ws[c4+3][row]=wvv.w;
    }
    __syncthreads();
    #pragma unroll
    for (int kk=0;kk<16;++kk){
      float xa[8], wb[8];
      #pragma unroll
      for (int i=0;i<8;++i) xa[i]=Xs[kk][trow+i];
      #pragma unroll
      for (int j=0;j<8;++j) wb[j]=Ws[kk][tcol+j];
      #pragma unroll
      for (int i=0;i<8;++i)
        #pragma unroll
        for (int j=0;j<8;++j)
          acc[i][j] = fmaf(xa[i], wb[j], acc[i][j]);
    }
    __syncthreads();
  }
  float bb[8];
  #pragma unroll
  for (int j=0;j<8;++j) bb[j]=bias[bn+tcol+j];
  #pragma unroll
  for (int i=0;i<8;++i){
    float* yr = Y + (size_t)(bm+trow+i)*Nd + bn + tcol;
    float4 o0, o1;
    o0.x=acc[i][0]+bb[0]; o0.y=acc[i][1]+bb[1]; o0.z=acc[i][2]+bb[2]; o0.w=acc[i][3]+bb[3];
    o1.x=acc[i][4]+bb[4]; o1.y=acc[i][5]+bb[5]; o1.z=acc[i][6]+bb[6]; o1.w=acc[i][7]+bb[7];
    *(float4*)(yr)   = o0;
    *(float4*)(yr+4) = o1;
  }
}

// ---------------- windowed attention with fused pair-MLP bias ----------------
// block = 256 threads = 16 queries x 16 heads; grid = (B*NW, max q-chunks)
__global__ __launch_bounds__(256) void attn_kernel(
    const float* __restrict__ qkv, const float* __restrict__ coords,
    const float4* __restrict__ w14, const float* __restrict__ pw2,
    const float* __restrict__ pb2,
    const int* __restrict__ counts, const int* __restrict__ offsets,
    const int* __restrict__ sidx, float* __restrict__ aout)
{
  const int bwi = blockIdx.x;
  const int b = bwi / NW;
  const int n = counts[bwi];
  const int q0 = blockIdx.y * QC;
  if (q0 >= n) return;
  const int off = offsets[bwi] + b*N_;
  const int tid = threadIdx.x;
  const int h  = tid & 15;
  const int qi = tid >> 4;

  __shared__ float s_bias[QC][KC][16];   // 32 KB
  __shared__ float s_qc[QC][3];
  __shared__ int   s_qidx[QC];
  __shared__ float s_kc[KC][3];
  __shared__ int   s_kidx[KC];

  const int qn = min(QC, n - q0);
  if (tid < QC) {
    int qg = 0;
    if (tid < qn) qg = sidx[off + q0 + tid];
    s_qidx[tid] = qg;
    s_qc[tid][0]=coords[(b*N_+qg)*3+0];
    s_qc[tid][1]=coords[(b*N_+qg)*3+1];
    s_qc[tid][2]=coords[(b*N_+qg)*3+2];
  }
  __syncthreads();

  const bool qv = (qi < qn);
  const float* qrow = qkv + ((size_t)(b*N_ + s_qidx[qi]))*1536 + h*32;
  float4 qreg[8];
  #pragma unroll
  for (int i=0;i<8;++i) qreg[i] = *(const float4*)(qrow + i*4);

  float mrun = -1e30f, lrun = 0.f;
  float4 acc[8];
  #pragma unroll
  for (int i=0;i<8;++i) acc[i]=make_float4(0.f,0.f,0.f,0.f);
  const float b2h = pb2[h];
  const float scale = 0.17677669529663687f;   // 32^-0.5

  for (int kc0=0; kc0<n; kc0+=KC) {
    const int kn = min(KC, n-kc0);
    __syncthreads();                      // protect s_kc/s_kidx from prev phase B
    if (tid < KC) {
      int kg = 0;
      if (tid < kn) kg = sidx[off + kc0 + tid];
      s_kidx[tid]=kg;
      s_kc[tid][0]=coords[(b*N_+kg)*3+0];
      s_kc[tid][1]=coords[(b*N_+kg)*3+1];
      s_kc[tid][2]=coords[(b*N_+kg)*3+2];
    }
    __syncthreads();
    // ---- phase A: pair MLP bias, one thread per pair (2 pairs/thread) ----
    #pragma unroll
    for (int rep=0; rep<2; ++rep) {
      const int p  = tid + rep*256;       // 0..511
      const int pq = p >> 5, pk = p & 31;
      if (pq < qn && pk < kn) {
        const float ox = s_qc[pq][0]-s_kc[pk][0];
        const float oy = s_qc[pq][1]-s_kc[pk][1];
        const float oz = s_qc[pq][2]-s_kc[pk][2];
        float bh[16];
        #pragma unroll
        for (int t=0;t<16;++t) bh[t]=0.f;
        for (int u4=0; u4<32; ++u4) {     // 128 hidden units, 4 at a time
          float g[4];
          #pragma unroll
          for (int r=0;r<4;++r) {
            const float4 wvv = w14[u4*4+r];               // wave-uniform -> s_load
            const float t = fmaf(ox,wvv.x, fmaf(oy,wvv.y, fmaf(oz,wvv.z, wvv.w)));
            g[r] = 0.5f*t*(1.0f + erff(t*0.70710678118654752f));  // exact GELU
          }
          #pragma unroll
          for (int hh=0; hh<16; ++hh) {
            const float4 w2v = *(const float4*)(pw2 + hh*128 + u4*4);  // uniform
            bh[hh] = fmaf(g[0],w2v.x, fmaf(g[1],w2v.y, fmaf(g[2],w2v.z, fmaf(g[3],w2v.w, bh[hh]))));
          }
        }
        #pragma unroll
        for (int t=0;t<16;++t) s_bias[pq][pk][t] = bh[t];
      }
    }
    __syncthreads();
    // ---- phase B: online-softmax attention, thread = (query, head) ----
    if (qv) {
      for (int kj=0; kj<kn; ++kj) {
        const int kg = s_kidx[kj];
        const float* krow = qkv + ((size_t)(b*N_+kg))*1536 + 512 + h*32;
        float dot = 0.f;
        #pragma unroll
        for (int i=0;i<8;++i) {
          const float4 kvv = *(const float4*)(krow + i*4);
          dot = fmaf(qreg[i].x,kvv.x, fmaf(qreg[i].y,kvv.y,
                fmaf(qreg[i].z,kvv.z, fmaf(qreg[i].w,kvv.w, dot))));
        }
        const float s  = fmaf(dot, scale, s_bias[qi][kj][h] + b2h);
        const float mn = fmaxf(mrun, s);
        const float sc = __expf(mrun - mn);
        const float pp = __expf(s - mn);
        lrun = lrun*sc + pp;
        const float* vrow = krow + 512;
        #pragma unroll
        for (int i=0;i<8;++i) {
          const float4 vv = *(const float4*)(vrow + i*4);
          acc[i].x = fmaf(acc[i].x, sc, pp*vv.x);
          acc[i].y = fmaf(acc[i].y, sc, pp*vv.y);
          acc[i].z = fmaf(acc[i].z, sc, pp*vv.z);
          acc[i].w = fmaf(acc[i].w, sc, pp*vv.w);
        }
        mrun = mn;
      }
    }
  }
  if (qv) {
    const float inv = 1.0f/lrun;
    float* orow = aout + ((size_t)(b*N_ + s_qidx[qi]))*C_ + h*32;
    #pragma unroll
    for (int i=0;i<8;++i) {
      float4 o; o.x=acc[i].x*inv; o.y=acc[i].y*inv; o.z=acc[i].z*inv; o.w=acc[i].w*inv;
      *(float4*)(orow + i*4) = o;
    }
  }
}

extern "C" void kernel_launch(void* const* d_in, const int* in_sizes, int n_in,
                              void* d_out, int out_size, void* d_ws, size_t ws_size,
                              hipStream_t stream)
{
  const float* coords = (const float*)d_in[0];
  const float* x      = (const float*)d_in[1];
  const float* qkv_w  = (const float*)d_in[2];
  const float* qkv_b  = (const float*)d_in[3];
  const float* proj_w = (const float*)d_in[4];
  const float* proj_b = (const float*)d_in[5];
  const float* pw1    = (const float*)d_in[6];
  const float* pb1    = (const float*)d_in[7];
  const float* pw2    = (const float*)d_in[8];
  const float* pb2    = (const float*)d_in[9];
  float* out = (float*)d_out;

  // workspace layout (all written every call; ~16.8 MB)
  float* qkv   = (float*)d_ws;                          // 2048 x 1536
  float* aout  = qkv + (size_t)B_*N_*3*C_;              // 2048 x 512
  int*   counts  = (int*)(aout + (size_t)B_*N_*C_);     // 54 (pad 64)
  int*   offsets = counts + 64;                         // 54 (pad 64)
  int*   sidx    = offsets + 64;                        // 2048
  float4* w14    = (float4*)(sidx + 2048);              // 128 float4 (16B aligned)

  hipLaunchKernelGGL(win_kernel,  dim3(B_),     dim3(1024), 0, stream,
                     coords, counts, offsets, sidx);
  hipLaunchKernelGGL(pack_kernel, dim3(1),      dim3(128),  0, stream,
                     pw1, pb1, w14);
  hipLaunchKernelGGL(gemm_bt,     dim3(16,12),  dim3(256),  0, stream,
                     x, qkv_w, qkv_b, qkv, 2048, 1536, 512);
  hipLaunchKernelGGL(attn_kernel, dim3(B_*NW,64), dim3(256), 0, stream,
                     qkv, coords, w14, pw2, pb2, counts, offsets, sidx, aout);
  hipLaunchKernelGGL(gemm_bt,     dim3(16,4),   dim3(256),  0, stream,
                     aout, proj_w, proj_b, out, 2048, 512, 512);
}